// Round 3
// baseline (345.078 us; speedup 1.0000x reference)
//
#include <hip/hip_runtime.h>
#include <hip/hip_cooperative_groups.h>

namespace cg = cooperative_groups;

#define N_NODES 50000
#define N_EDGES 800000
#define IN_CH   256
#define OUT_CH  128

#define NB        391          // coarse buckets of 128 nodes: ceil(50000/128)
#define CAP       3072         // record capacity per bucket (mean 2048, sd ~45)
#define L1_CHUNK  2048
#define NBUK      ((N_EDGES + L1_CHUNK - 1) / L1_CHUNK)   // 391 bucket chunks
#define GBM       64
#define NGEMM     ((N_NODES + GBM - 1) / GBM)             // 782 gemm tiles
#define GBK 32
#define LDK 40   // padded row length (bf16 elems); 80B stride keeps 16B align

#define GRID   512             // 2 blocks/CU x 256 CU -> cooperative launch
                               // co-residency check passes with huge margin
#define QCAP   1024            // quarter capacity: mean 512, sd ~23

typedef __attribute__((ext_vector_type(8))) short short8;   // 8 bf16 (4 VGPRs)
typedef __attribute__((ext_vector_type(4))) float f32x4;

__device__ __forceinline__ short f2bf(float f) {
    unsigned u = __float_as_uint(f);
    unsigned r = (u + 0x7fffu + ((u >> 16) & 1u)) >> 16;    // RNE
    return (short)r;
}

// One persistent cooperative kernel: phase 1 (GEMM tiles + edge bucketing)
// -> grid.sync() -> phase 2 (fine sort + gather-mean). Removes two kernel
// launch boundaries and their machine-drain tails; convert_w is gone
// (B staged straight from fp32 W, 128 KB L2-resident).
// __launch_bounds__(256,2): VGPR<=256, LDS 2x15.4KB -> the cooperative
// launch's 2-blocks/CU requirement is guaranteed satisfiable.
__global__ __launch_bounds__(256, 2) void fused(const float* __restrict__ x,
                                                const float* __restrict__ W,
                                                const float* __restrict__ bias,
                                                short* __restrict__ linbf,
                                                const int* __restrict__ src,
                                                const int* __restrict__ dst,
                                                int* __restrict__ bcnt,
                                                unsigned* __restrict__ rec,
                                                float* __restrict__ out) {
    __shared__ __align__(16) char smem[15360];
    const int tid = threadIdx.x;

    // ===================== PHASE 1: GEMM + bucket-scatter =====================
    for (int item = blockIdx.x; item < NGEMM + NBUK; item += GRID) {
        if (item < NGEMM) {
            // ---------------- GEMM tile (64 x 128) ----------------
            short* As = (short*)smem;            // 5120 B:  [m][k] tile (64 x 32)
            short* Bs = (short*)(smem + 5120);   // 10240 B: [n][k] tile (128 x 32)

            const int m0  = item * GBM;
            const int w    = tid >> 6;
            const int lane = tid & 63;
            const int lm   = lane & 15;
            const int lq   = lane >> 4;
            const int wrow = (w >> 1) * 32;
            const int wcol = (w & 1) * 64;

            f32x4 acc[2][4];
#pragma unroll
            for (int i = 0; i < 2; ++i)
#pragma unroll
                for (int j = 0; j < 4; ++j) acc[i][j] = (f32x4)(0.0f);

            const int arow = tid >> 2;        // A staging row (0..63)
            const int aq   = tid & 3;         // which 8-k group
            const int brow = tid >> 1;        // B staging row (0..127)
            const int bhalf = tid & 1;        // which 16-k half

            for (int k0 = 0; k0 < IN_CH; k0 += GBK) {
                // stage A: 64 rows x 32 k, fp32 -> bf16 (32 B / thread)
                {
                    float4 v0 = make_float4(0.f,0.f,0.f,0.f), v1 = v0;
                    if (m0 + arow < N_NODES) {
                        const float* xp = x + (size_t)(m0 + arow) * IN_CH + k0 + aq * 8;
                        v0 = ((const float4*)xp)[0];
                        v1 = ((const float4*)xp)[1];
                    }
                    short8 s;
                    s[0]=f2bf(v0.x); s[1]=f2bf(v0.y); s[2]=f2bf(v0.z); s[3]=f2bf(v0.w);
                    s[4]=f2bf(v1.x); s[5]=f2bf(v1.y); s[6]=f2bf(v1.z); s[7]=f2bf(v1.w);
                    *(short8*)&As[arow * LDK + aq * 8] = s;
                }
                // stage B: 128 n x 32 k straight from fp32 W (L2-resident 128 KB)
                {
                    const float* wp = W + (size_t)brow * IN_CH + k0 + bhalf * 16;
                    float4 w0 = ((const float4*)wp)[0];
                    float4 w1 = ((const float4*)wp)[1];
                    float4 w2 = ((const float4*)wp)[2];
                    float4 w3 = ((const float4*)wp)[3];
                    short8 s0, s1;
                    s0[0]=f2bf(w0.x); s0[1]=f2bf(w0.y); s0[2]=f2bf(w0.z); s0[3]=f2bf(w0.w);
                    s0[4]=f2bf(w1.x); s0[5]=f2bf(w1.y); s0[6]=f2bf(w1.z); s0[7]=f2bf(w1.w);
                    s1[0]=f2bf(w2.x); s1[1]=f2bf(w2.y); s1[2]=f2bf(w2.z); s1[3]=f2bf(w2.w);
                    s1[4]=f2bf(w3.x); s1[5]=f2bf(w3.y); s1[6]=f2bf(w3.z); s1[7]=f2bf(w3.w);
                    *(short8*)&Bs[brow * LDK + bhalf * 16]     = s0;
                    *(short8*)&Bs[brow * LDK + bhalf * 16 + 8] = s1;
                }
                __syncthreads();

                short8 af[2], bfr[4];
#pragma unroll
                for (int rt = 0; rt < 2; ++rt)
                    af[rt] = *(const short8*)&As[(wrow + rt * 16 + lm) * LDK + lq * 8];
#pragma unroll
                for (int ct = 0; ct < 4; ++ct)
                    bfr[ct] = *(const short8*)&Bs[(wcol + ct * 16 + lm) * LDK + lq * 8];
#pragma unroll
                for (int rt = 0; rt < 2; ++rt)
#pragma unroll
                    for (int ct = 0; ct < 4; ++ct)
                        acc[rt][ct] = __builtin_amdgcn_mfma_f32_16x16x32_bf16(
                            af[rt], bfr[ct], acc[rt][ct], 0, 0, 0);
                __syncthreads();
            }

            // epilogue: D row = lq*4 + r, col = lm
#pragma unroll
            for (int ct = 0; ct < 4; ++ct) {
                int gcol = wcol + ct * 16 + lm;
                float bv = bias[gcol];
#pragma unroll
                for (int rt = 0; rt < 2; ++rt) {
#pragma unroll
                    for (int r = 0; r < 4; ++r) {
                        int grow = m0 + wrow + rt * 16 + lq * 4 + r;
                        if (grow < N_NODES)
                            linbf[(size_t)grow * OUT_CH + gcol] = f2bf(acc[rt][ct][r] + bv);
                    }
                }
            }
        } else {
            // ---------------- bucket-scatter chunk ----------------
            // packed record: src (16b) | (dst&127)<<16 (7b) | (dst>>7)<<23 (9b)
            int* lhist       = (int*)smem;             // 1564 B
            int* lscan       = (int*)(smem + 1568);    // 1564 B
            int* lbase       = (int*)(smem + 3136);    // 1564 B
            unsigned* staged = (unsigned*)(smem + 4704); // 8192 B

            const int blk = item - NGEMM;
            const int e0  = blk * L1_CHUNK;
            const int total = min(L1_CHUNK, N_EDGES - e0);

            for (int i = tid; i < NB; i += 256) lhist[i] = 0;
            __syncthreads();

            unsigned mypk[8];
            int myr[8];
            int myb[8];
#pragma unroll
            for (int j = 0; j < 8; ++j) {
                int i = tid + j * 256;
                myb[j] = -1;
                if (i < total) {
                    unsigned d = (unsigned)dst[e0 + i];
                    unsigned s = (unsigned)src[e0 + i];
                    int b = (int)(d >> 7);
                    myb[j] = b;
                    mypk[j] = s | ((d & 127u) << 16) | ((unsigned)b << 23);
                    myr[j] = atomicAdd(&lhist[b], 1);
                }
            }
            __syncthreads();

            // exclusive scan lhist -> lscan (wave 0, 7 chunks of 64)
            if (tid < 64) {
                int carry = 0;
                for (int c = 0; c < NB; c += 64) {
                    int idx = c + tid;
                    int v = (idx < NB) ? lhist[idx] : 0;
                    int incl = v;
#pragma unroll
                    for (int s = 1; s < 64; s <<= 1) {
                        int t = __shfl_up(incl, s, 64);
                        if (tid >= s) incl += t;
                    }
                    if (idx < NB) lscan[idx] = carry + incl - v;
                    carry += __shfl(incl, 63, 64);
                }
            }
            __syncthreads();

            // reserve global space (one atomic per nonempty bucket) + stage locally
            for (int bkt = tid; bkt < NB; bkt += 256) {
                int c = lhist[bkt];
                lbase[bkt] = c ? atomicAdd(&bcnt[bkt], c) : 0;
            }
#pragma unroll
            for (int j = 0; j < 8; ++j) {
                if (myb[j] >= 0)
                    staged[lscan[myb[j]] + myr[j]] = mypk[j];
            }
            __syncthreads();

            // write out: bucket-grouped runs -> mostly-contiguous global stores
            for (int p = tid; p < total; p += 256) {
                unsigned r = staged[p];
                int b = (int)(r >> 23);
                int gpos = lbase[b] + (p - lscan[b]);
                if (gpos < CAP)
                    rec[(size_t)b * CAP + gpos] = r;
            }
        }
        __syncthreads();   // smem reuse guard between persistent items
    }

    // ===================== grid-wide sync (cooperative) =====================
    __threadfence();           // release: make linbf/rec/bcnt visible cross-XCD
    cg::this_grid().sync();
    __threadfence();           // acquire: don't read stale L1/L2 lines

    // ===================== PHASE 2: fine sort + gather-mean ================
    {
        unsigned short* ssrc = (unsigned short*)smem;   // 2048 B
        int* fh = (int*)(smem + 2048);
        int* fo = (int*)(smem + 2176);
        int* fc = (int*)(smem + 2304);

        for (int qq = blockIdx.x; qq < NB * 4; qq += GRID) {
            const int b  = qq >> 2;            // coarse bucket
            const int lo = (qq & 3) * 32;      // first fine node of this quarter
            const int cnt = min(bcnt[b], CAP);
            const unsigned* rp = rec + (size_t)b * CAP;

            __syncthreads();                   // guard vs previous quarter's readers
            if (tid < 32) fh[tid] = 0;
            __syncthreads();

            // pass 1: filter-histogram this quarter's fine nodes
            for (int i = tid; i < cnt; i += 256) {
                int f = (int)((rp[i] >> 16) & 127u) - lo;
                if ((unsigned)f < 32u) atomicAdd(&fh[f], 1);
            }
            __syncthreads();

            // exclusive scan of 32 counters (lanes 0..31 of wave 0)
            if (tid < 32) {
                int v = fh[tid], incl = v;
#pragma unroll
                for (int s = 1; s < 32; s <<= 1) {
                    int t = __shfl_up(incl, s, 32);
                    if (tid >= s) incl += t;
                }
                fo[tid] = incl - v;
                fc[tid] = incl - v;
            }
            __syncthreads();

            // pass 2: filter-scatter srcs into sorted LDS order
            for (int i = tid; i < cnt; i += 256) {
                unsigned r = rp[i];
                int f = (int)((r >> 16) & 127u) - lo;
                if ((unsigned)f < 32u) {
                    int p = atomicAdd(&fc[f], 1);
                    if (p < QCAP) ssrc[p] = (unsigned short)(r & 0xffffu);
                }
            }
            __syncthreads();

            // gather phase: 16 lanes per node, 16 nodes in flight, 2 rounds
            const int l = tid & 15;
#pragma unroll 1
            for (int g = 0; g < 2; ++g) {
                int fn = g * 16 + (tid >> 4);          // local node 0..31
                int n = b * 128 + lo + fn;
                if (n >= N_NODES) continue;
                const int beg = fo[fn];
                const int deg = fh[fn];
                const int end = beg + deg;

                float a[8];
#pragma unroll
                for (int j = 0; j < 8; ++j) a[j] = 0.0f;

                int i = beg;
                for (; i + 3 < end; i += 4) {
                    uint4 u[4];
#pragma unroll
                    for (int e = 0; e < 4; ++e) {
                        int s = ssrc[i + e];
                        u[e] = *(const uint4*)&linbf[(size_t)s * OUT_CH + l * 8];
                    }
#pragma unroll
                    for (int e = 0; e < 4; ++e) {
                        const unsigned* p = (const unsigned*)&u[e];
#pragma unroll
                        for (int j = 0; j < 4; ++j) {
                            a[2*j]   += __uint_as_float(p[j] << 16);
                            a[2*j+1] += __uint_as_float(p[j] & 0xffff0000u);
                        }
                    }
                }
                for (; i < end; ++i) {
                    int s = ssrc[i];
                    uint4 u0 = *(const uint4*)&linbf[(size_t)s * OUT_CH + l * 8];
                    const unsigned* p0 = (const unsigned*)&u0;
#pragma unroll
                    for (int j = 0; j < 4; ++j) {
                        a[2*j]   += __uint_as_float(p0[j] << 16);
                        a[2*j+1] += __uint_as_float(p0[j] & 0xffff0000u);
                    }
                }
                float inv = 1.0f / (float)(deg > 1 ? deg : 1);
                float4 o0, o1;
                o0.x = a[0]*inv; o0.y = a[1]*inv; o0.z = a[2]*inv; o0.w = a[3]*inv;
                o1.x = a[4]*inv; o1.y = a[5]*inv; o1.z = a[6]*inv; o1.w = a[7]*inv;
                float* op = &out[(size_t)n * OUT_CH + l * 8];
                ((float4*)op)[0] = o0;
                ((float4*)op)[1] = o1;
            }
        }
    }
}

extern "C" void kernel_launch(void* const* d_in, const int* in_sizes, int n_in,
                              void* d_out, int out_size, void* d_ws, size_t ws_size,
                              hipStream_t stream) {
    const float* x  = (const float*)d_in[0];
    const int*   ei = (const int*)d_in[1];     // [2][E]: src then dst
    const float* W  = (const float*)d_in[2];
    const float* bs = (const float*)d_in[3];
    float* out = (float*)d_out;

    const int* src = ei;
    const int* dst = ei + N_EDGES;

    // workspace: linbf 12.8MB | rec 4.8MB | bcnt(512)
    char* ws = (char*)d_ws;
    short*    linbf = (short*)ws;    ws += ((size_t)N_NODES * OUT_CH * sizeof(short) + 255) & ~255ull;
    unsigned* rec   = (unsigned*)ws; ws += ((size_t)NB * CAP * sizeof(unsigned) + 255) & ~255ull;
    int*      bcnt  = (int*)ws;

    hipMemsetAsync(bcnt, 0, 512 * sizeof(int), stream);

    void* kargs[] = {(void*)&x, (void*)&W, (void*)&bs, (void*)&linbf,
                     (void*)&src, (void*)&dst, (void*)&bcnt, (void*)&rec,
                     (void*)&out};
    hipLaunchCooperativeKernel((void*)fused, dim3(GRID), dim3(256),
                               kargs, 0, stream);
}

// Round 5
// 146.961 us; speedup vs baseline: 2.3481x; 2.3481x over previous
//
#include <hip/hip_runtime.h>

#define N_NODES 50000
#define N_EDGES 800000
#define IN_CH   256
#define OUT_CH  128

#define NB        391          // coarse buckets of 128 nodes: ceil(50000/128)
#define CAP       3072         // record capacity per bucket (mean 2048, sd ~45)
#define L1_CHUNK  2048
#define NBUK      ((N_EDGES + L1_CHUNK - 1) / L1_CHUNK)   // 391 bucket chunks
#define GBM       64
#define NGEMM     ((N_NODES + GBM - 1) / GBM)             // 782 gemm tiles
#define GBK 32
#define LDK 40   // padded row length (bf16 elems); 80B stride keeps 16B align

typedef __attribute__((ext_vector_type(8))) short short8;   // 8 bf16 (4 VGPRs)
typedef __attribute__((ext_vector_type(4))) float f32x4;

__device__ __forceinline__ short f2bf(float f) {
    unsigned u = __float_as_uint(f);
    unsigned r = (u + 0x7fffu + ((u >> 16) & 1u)) >> 16;    // RNE
    return (short)r;
}

// R4 post-mortem: cooperative fusion is dead — coop launch carries ~52us
// overhead per iteration (R3: 345.1 total - 249.3 kernel - 41.5 poison
// fill) and the GRID=2048 residency check failed outright (absmax 1.32 =
// all-zero output). Revert to the verified non-coop R0 structure, minus
// the convert_w kernel: B is staged straight from fp32 W (128 KB,
// L2-resident) with inline RNE conversion — this exact staging code
// passed correctness in R3's phase 1.

// ---------------- fused: MFMA GEMM (blocks 0..781) + edge bucketing ------
__global__ __launch_bounds__(256) void gemm_bucket(const float* __restrict__ x,
                                                   const float* __restrict__ W,
                                                   const float* __restrict__ bias,
                                                   short* __restrict__ linbf,
                                                   const int* __restrict__ src,
                                                   const int* __restrict__ dst,
                                                   int* __restrict__ bcnt,
                                                   unsigned* __restrict__ rec) {
    __shared__ __align__(16) char smem[15360];
    const int tid = threadIdx.x;

    if (blockIdx.x < NGEMM) {
        // ================= GEMM part =================
        short* As = (short*)smem;            // 5120 B:  [m][k] tile (64 x 32)
        short* Bs = (short*)(smem + 5120);   // 10240 B: [n][k] tile (128 x 32)

        const int m0  = blockIdx.x * GBM;
        const int w    = tid >> 6;
        const int lane = tid & 63;
        const int lm   = lane & 15;
        const int lq   = lane >> 4;
        const int wrow = (w >> 1) * 32;
        const int wcol = (w & 1) * 64;

        f32x4 acc[2][4];
#pragma unroll
        for (int i = 0; i < 2; ++i)
#pragma unroll
            for (int j = 0; j < 4; ++j) acc[i][j] = (f32x4)(0.0f);

        const int arow = tid >> 2;        // A staging row (0..63)
        const int aq   = tid & 3;         // which 8-k group
        const int brow = tid >> 1;        // B staging row (0..127)
        const int bhalf = tid & 1;        // which 16-k half

        for (int k0 = 0; k0 < IN_CH; k0 += GBK) {
            // stage A: 64 rows x 32 k, fp32 -> bf16 (32 B / thread)
            {
                float4 v0 = make_float4(0.f,0.f,0.f,0.f), v1 = v0;
                if (m0 + arow < N_NODES) {
                    const float* xp = x + (size_t)(m0 + arow) * IN_CH + k0 + aq * 8;
                    v0 = ((const float4*)xp)[0];
                    v1 = ((const float4*)xp)[1];
                }
                short8 s;
                s[0]=f2bf(v0.x); s[1]=f2bf(v0.y); s[2]=f2bf(v0.z); s[3]=f2bf(v0.w);
                s[4]=f2bf(v1.x); s[5]=f2bf(v1.y); s[6]=f2bf(v1.z); s[7]=f2bf(v1.w);
                *(short8*)&As[arow * LDK + aq * 8] = s;
            }
            // stage B: 128 n x 32 k straight from fp32 W (L2-resident 128 KB)
            {
                const float* wp = W + (size_t)brow * IN_CH + k0 + bhalf * 16;
                float4 w0 = ((const float4*)wp)[0];
                float4 w1 = ((const float4*)wp)[1];
                float4 w2 = ((const float4*)wp)[2];
                float4 w3 = ((const float4*)wp)[3];
                short8 s0, s1;
                s0[0]=f2bf(w0.x); s0[1]=f2bf(w0.y); s0[2]=f2bf(w0.z); s0[3]=f2bf(w0.w);
                s0[4]=f2bf(w1.x); s0[5]=f2bf(w1.y); s0[6]=f2bf(w1.z); s0[7]=f2bf(w1.w);
                s1[0]=f2bf(w2.x); s1[1]=f2bf(w2.y); s1[2]=f2bf(w2.z); s1[3]=f2bf(w2.w);
                s1[4]=f2bf(w3.x); s1[5]=f2bf(w3.y); s1[6]=f2bf(w3.z); s1[7]=f2bf(w3.w);
                *(short8*)&Bs[brow * LDK + bhalf * 16]     = s0;
                *(short8*)&Bs[brow * LDK + bhalf * 16 + 8] = s1;
            }
            __syncthreads();

            short8 af[2], bfr[4];
#pragma unroll
            for (int rt = 0; rt < 2; ++rt)
                af[rt] = *(const short8*)&As[(wrow + rt * 16 + lm) * LDK + lq * 8];
#pragma unroll
            for (int ct = 0; ct < 4; ++ct)
                bfr[ct] = *(const short8*)&Bs[(wcol + ct * 16 + lm) * LDK + lq * 8];
#pragma unroll
            for (int rt = 0; rt < 2; ++rt)
#pragma unroll
                for (int ct = 0; ct < 4; ++ct)
                    acc[rt][ct] = __builtin_amdgcn_mfma_f32_16x16x32_bf16(
                        af[rt], bfr[ct], acc[rt][ct], 0, 0, 0);
            __syncthreads();
        }

        // epilogue: D row = lq*4 + r, col = lm
#pragma unroll
        for (int ct = 0; ct < 4; ++ct) {
            int gcol = wcol + ct * 16 + lm;
            float bv = bias[gcol];
#pragma unroll
            for (int rt = 0; rt < 2; ++rt) {
#pragma unroll
                for (int r = 0; r < 4; ++r) {
                    int grow = m0 + wrow + rt * 16 + lq * 4 + r;
                    if (grow < N_NODES)
                        linbf[(size_t)grow * OUT_CH + gcol] = f2bf(acc[rt][ct][r] + bv);
                }
            }
        }
    } else {
        // ================= bucket-scatter part =================
        // packed record: src (16b) | (dst&127)<<16 (7b) | (dst>>7)<<23 (9b)
        int* lhist       = (int*)smem;             // 1564 B
        int* lscan       = (int*)(smem + 1568);    // 1564 B
        int* lbase       = (int*)(smem + 3136);    // 1564 B
        unsigned* staged = (unsigned*)(smem + 4704); // 8192 B

        const int blk = blockIdx.x - NGEMM;
        const int e0  = blk * L1_CHUNK;
        const int total = min(L1_CHUNK, N_EDGES - e0);

        for (int i = tid; i < NB; i += 256) lhist[i] = 0;
        __syncthreads();

        unsigned mypk[8];
        int myr[8];
        int myb[8];
#pragma unroll
        for (int j = 0; j < 8; ++j) {
            int i = tid + j * 256;
            myb[j] = -1;
            if (i < total) {
                unsigned d = (unsigned)dst[e0 + i];
                unsigned s = (unsigned)src[e0 + i];
                int b = (int)(d >> 7);
                myb[j] = b;
                mypk[j] = s | ((d & 127u) << 16) | ((unsigned)b << 23);
                myr[j] = atomicAdd(&lhist[b], 1);
            }
        }
        __syncthreads();

        // exclusive scan lhist -> lscan (wave 0, 7 chunks of 64)
        if (tid < 64) {
            int carry = 0;
            for (int c = 0; c < NB; c += 64) {
                int idx = c + tid;
                int v = (idx < NB) ? lhist[idx] : 0;
                int incl = v;
#pragma unroll
                for (int s = 1; s < 64; s <<= 1) {
                    int t = __shfl_up(incl, s, 64);
                    if (tid >= s) incl += t;
                }
                if (idx < NB) lscan[idx] = carry + incl - v;
                carry += __shfl(incl, 63, 64);
            }
        }
        __syncthreads();

        // reserve global space (one atomic per nonempty bucket) + stage locally
        for (int bkt = tid; bkt < NB; bkt += 256) {
            int c = lhist[bkt];
            lbase[bkt] = c ? atomicAdd(&bcnt[bkt], c) : 0;
        }
#pragma unroll
        for (int j = 0; j < 8; ++j) {
            if (myb[j] >= 0)
                staged[lscan[myb[j]] + myr[j]] = mypk[j];
        }
        __syncthreads();

        // write out: bucket-grouped runs -> mostly-contiguous global stores
        for (int p = tid; p < total; p += 256) {
            unsigned r = staged[p];
            int b = (int)(r >> 23);
            int gpos = lbase[b] + (p - lscan[b]);
            if (gpos < CAP)
                rec[(size_t)b * CAP + gpos] = r;
        }
    }
}

// ---------- fused: fine sort (LDS) + gather-mean for 128 nodes/block -----
// 1024 threads: 16 waves/block for latency hiding on the random-row gather.
// (R0's verified version — R1's 256-thr restructure was neutral-to-worse.)
#define FG_THR 1024
__global__ __launch_bounds__(FG_THR) void fine_gather(const int* __restrict__ bcnt,
                                                      const unsigned* __restrict__ rec,
                                                      const short* __restrict__ linbf,
                                                      float* __restrict__ out) {
    __shared__ unsigned srec[CAP];          // 12288 B
    __shared__ unsigned short ssrc[CAP];    // 6144 B
    __shared__ int fh[128], fo[128], fc[128];

    const int b = blockIdx.x;
    const int tid = threadIdx.x;
    const int cnt = min(bcnt[b], CAP);

    // load records, histogram fine node (dst & 127)
    for (int i = tid; i < cnt; i += FG_THR)
        srec[i] = rec[(size_t)b * CAP + i];
    if (tid < 128) fh[tid] = 0;
    __syncthreads();

    for (int i = tid; i < cnt; i += FG_THR)
        atomicAdd(&fh[(srec[i] >> 16) & 127u], 1);
    __syncthreads();

    // exclusive scan of 128 counters (wave 0)
    if (tid < 64) {
        int carry = 0;
        for (int c = 0; c < 128; c += 64) {
            int v = fh[c + tid];
            int incl = v;
#pragma unroll
            for (int s = 1; s < 64; s <<= 1) {
                int t = __shfl_up(incl, s, 64);
                if (tid >= s) incl += t;
            }
            fo[c + tid] = carry + incl - v;
            carry += __shfl(incl, 63, 64);
        }
    }
    __syncthreads();
    if (tid < 128) fc[tid] = fo[tid];
    __syncthreads();

    // sorted scatter into LDS ssrc
    for (int i = tid; i < cnt; i += FG_THR) {
        unsigned r = srec[i];
        int p = atomicAdd(&fc[(r >> 16) & 127u], 1);
        ssrc[p] = (unsigned short)(r & 0xffffu);
    }
    __syncthreads();

    // gather phase: 16 lanes per node, 64 nodes in flight, 2 rounds
    const int l = tid & 15;
#pragma unroll 1
    for (int g = 0; g < 2; ++g) {
        int nl = g * 64 + (tid >> 4);          // local node 0..127
        int n = b * 128 + nl;
        if (n >= N_NODES) continue;
        const int beg = fo[nl];
        const int deg = fh[nl];
        const int end = beg + deg;

        float a[8];
#pragma unroll
        for (int j = 0; j < 8; ++j) a[j] = 0.0f;

        int i = beg;
        for (; i + 3 < end; i += 4) {
            uint4 u[4];
#pragma unroll
            for (int e = 0; e < 4; ++e) {
                int s = ssrc[i + e];
                u[e] = *(const uint4*)&linbf[(size_t)s * OUT_CH + l * 8];
            }
#pragma unroll
            for (int e = 0; e < 4; ++e) {
                const unsigned* p = (const unsigned*)&u[e];
#pragma unroll
                for (int j = 0; j < 4; ++j) {
                    a[2*j]   += __uint_as_float(p[j] << 16);
                    a[2*j+1] += __uint_as_float(p[j] & 0xffff0000u);
                }
            }
        }
        for (; i < end; ++i) {
            int s = ssrc[i];
            uint4 u0 = *(const uint4*)&linbf[(size_t)s * OUT_CH + l * 8];
            const unsigned* p0 = (const unsigned*)&u0;
#pragma unroll
            for (int j = 0; j < 4; ++j) {
                a[2*j]   += __uint_as_float(p0[j] << 16);
                a[2*j+1] += __uint_as_float(p0[j] & 0xffff0000u);
            }
        }
        float inv = 1.0f / (float)(deg > 1 ? deg : 1);
        float4 o0, o1;
        o0.x = a[0]*inv; o0.y = a[1]*inv; o0.z = a[2]*inv; o0.w = a[3]*inv;
        o1.x = a[4]*inv; o1.y = a[5]*inv; o1.z = a[6]*inv; o1.w = a[7]*inv;
        float* op = &out[(size_t)n * OUT_CH + l * 8];
        ((float4*)op)[0] = o0;
        ((float4*)op)[1] = o1;
    }
}

extern "C" void kernel_launch(void* const* d_in, const int* in_sizes, int n_in,
                              void* d_out, int out_size, void* d_ws, size_t ws_size,
                              hipStream_t stream) {
    const float* x  = (const float*)d_in[0];
    const int*   ei = (const int*)d_in[1];     // [2][E]: src then dst
    const float* W  = (const float*)d_in[2];
    const float* b  = (const float*)d_in[3];
    float* out = (float*)d_out;

    const int* src = ei;
    const int* dst = ei + N_EDGES;

    // workspace: linbf 12.8MB | rec 4.8MB | bcnt(512)
    char* ws = (char*)d_ws;
    short*    linbf = (short*)ws;    ws += ((size_t)N_NODES * OUT_CH * sizeof(short) + 255) & ~255ull;
    unsigned* rec   = (unsigned*)ws; ws += ((size_t)NB * CAP * sizeof(unsigned) + 255) & ~255ull;
    int*      bcnt  = (int*)ws;

    hipMemsetAsync(bcnt, 0, 512 * sizeof(int), stream);
    gemm_bucket<<<NGEMM + NBUK, 256, 0, stream>>>(x, W, b, linbf, src, dst, bcnt, rec);
    fine_gather<<<NB, FG_THR, 0, stream>>>(bcnt, rec, linbf, out);
}

// Round 6
// 146.627 us; speedup vs baseline: 2.3534x; 1.0023x over previous
//
#include <hip/hip_runtime.h>

#define N_NODES 50000
#define N_EDGES 800000
#define IN_CH   256
#define OUT_CH  128

#define NB        391          // coarse buckets of 128 nodes: ceil(50000/128)
#define CAP       3072         // record capacity per bucket (mean 2048, sd ~45)
#define L1_CHUNK  2048
#define NBUK      ((N_EDGES + L1_CHUNK - 1) / L1_CHUNK)   // 391 bucket chunks
#define GBM       64
#define NGEMM     ((N_NODES + GBM - 1) / GBM)             // 782 gemm tiles
#define GBK 32
#define NKIT (IN_CH / GBK)     // 8 K-iterations
#define LDK 40   // padded row length (bf16 elems); 80B stride keeps 16B align

typedef __attribute__((ext_vector_type(8))) short short8;   // 8 bf16 (4 VGPRs)
typedef __attribute__((ext_vector_type(4))) float f32x4;

__device__ __forceinline__ short f2bf(float f) {
    unsigned u = __float_as_uint(f);
    unsigned r = (u + 0x7fffu + ((u >> 16) & 1u)) >> 16;    // RNE
    return (short)r;
}

// Raw barriers (m201-verified pattern): lgkmcnt(0) guarantees this wave's
// ds_writes landed before the barrier, but — unlike __syncthreads(), which
// the compiler lowers with a full s_waitcnt vmcnt(0) — in-flight GLOBAL
// loads (our K+1 register prefetch) stay in flight across the barrier.
__device__ __forceinline__ void bar_lgkm() {
    asm volatile("s_waitcnt lgkmcnt(0)" ::: "memory");
    __builtin_amdgcn_s_barrier();
    asm volatile("" ::: "memory");
}
__device__ __forceinline__ void bar_only() {
    asm volatile("" ::: "memory");
    __builtin_amdgcn_s_barrier();
    asm volatile("" ::: "memory");
}

// ------------- one-time: W fp32 -> bf16, zero bcnt -----------------------
// (R5 post-mortem: inlining this conversion into the GEMM's B-staging cost
// ~6us of per-iter VALU on the staging critical path; separate kernel is
// the measured winner — R0 141.3 vs R5 147.0.)
__global__ __launch_bounds__(256) void convert_w(const float* __restrict__ W,
                                                 short* __restrict__ Wbf,
                                                 int* __restrict__ bcnt) {
    int t = blockIdx.x * 256 + threadIdx.x;       // 4096 threads, 8 floats each
    const float* wp = W + t * 8;
    float4 v0 = ((const float4*)wp)[0];
    float4 v1 = ((const float4*)wp)[1];
    short8 s;
    s[0]=f2bf(v0.x); s[1]=f2bf(v0.y); s[2]=f2bf(v0.z); s[3]=f2bf(v0.w);
    s[4]=f2bf(v1.x); s[5]=f2bf(v1.y); s[6]=f2bf(v1.z); s[7]=f2bf(v1.w);
    *(short8*)&Wbf[t * 8] = s;
    if (t < NB) bcnt[t] = 0;
}

// ---------------- fused: MFMA GEMM (blocks 0..781) + edge bucketing ------
// R6: register-prefetch K-pipeline. Iter k's global loads were previously
// fully exposed (~900cy HBM) 8x per block because __syncthreads drains
// vmcnt. Now iter k+1's x/Wbf loads are issued before staging iter k, and
// raw lgkm-only barriers keep them in flight across the LDS handoff, so
// only iteration 0's latency is exposed.
__global__ __launch_bounds__(256) void gemm_bucket(const float* __restrict__ x,
                                                   const short* __restrict__ Wbf,
                                                   const float* __restrict__ bias,
                                                   short* __restrict__ linbf,
                                                   const int* __restrict__ src,
                                                   const int* __restrict__ dst,
                                                   int* __restrict__ bcnt,
                                                   unsigned* __restrict__ rec) {
    __shared__ __align__(16) char smem[15360];
    const int tid = threadIdx.x;

    if (blockIdx.x < NGEMM) {
        // ================= GEMM part =================
        short* As = (short*)smem;            // 5120 B:  [m][k] tile (64 x 32)
        short* Bs = (short*)(smem + 5120);   // 10240 B: [n][k] tile (128 x 32)

        const int m0  = blockIdx.x * GBM;
        const int w    = tid >> 6;
        const int lane = tid & 63;
        const int lm   = lane & 15;
        const int lq   = lane >> 4;
        const int wrow = (w >> 1) * 32;
        const int wcol = (w & 1) * 64;

        f32x4 acc[2][4];
#pragma unroll
        for (int i = 0; i < 2; ++i)
#pragma unroll
            for (int j = 0; j < 4; ++j) acc[i][j] = (f32x4)(0.0f);

        const int arow = tid >> 2;        // A staging row (0..63)
        const int aq   = tid & 3;         // which 8-k group
        const int brow = tid >> 1;        // B staging row (0..127)
        const int bhalf = tid & 1;        // which 16-k half

        const bool arowok = (m0 + arow < N_NODES);
        const float* xp = x + (size_t)(m0 + arow) * IN_CH + aq * 8;
        const short* wp = Wbf + (size_t)brow * IN_CH + bhalf * 16;

        // prologue: load K-tile 0 into registers
        float4 a0 = make_float4(0.f,0.f,0.f,0.f), a1 = a0;
        if (arowok) { a0 = ((const float4*)xp)[0]; a1 = ((const float4*)xp)[1]; }
        short8 wb0 = ((const short8*)wp)[0];
        short8 wb1 = ((const short8*)wp)[1];

#pragma unroll
        for (int kk = 0; kk < NKIT; ++kk) {
            // issue next K-tile's global loads FIRST (latency hides under
            // this iter's stage + MFMA; raw barriers don't drain vmcnt)
            float4 na0 = make_float4(0.f,0.f,0.f,0.f), na1 = na0;
            short8 nb0, nb1;
            if (kk + 1 < NKIT) {
                const float* xp2 = xp + (kk + 1) * GBK;
                if (arowok) { na0 = ((const float4*)xp2)[0]; na1 = ((const float4*)xp2)[1]; }
                const short* wp2 = wp + (kk + 1) * GBK;
                nb0 = ((const short8*)wp2)[0];
                nb1 = ((const short8*)wp2)[1];
            }

            // stage current K-tile from registers into LDS
            {
                short8 s;
                s[0]=f2bf(a0.x); s[1]=f2bf(a0.y); s[2]=f2bf(a0.z); s[3]=f2bf(a0.w);
                s[4]=f2bf(a1.x); s[5]=f2bf(a1.y); s[6]=f2bf(a1.z); s[7]=f2bf(a1.w);
                *(short8*)&As[arow * LDK + aq * 8] = s;
                *(short8*)&Bs[brow * LDK + bhalf * 16]     = wb0;
                *(short8*)&Bs[brow * LDK + bhalf * 16 + 8] = wb1;
            }
            bar_lgkm();      // ds_writes visible; prefetch still in flight

            short8 af[2], bfr[4];
#pragma unroll
            for (int rt = 0; rt < 2; ++rt)
                af[rt] = *(const short8*)&As[(wrow + rt * 16 + lm) * LDK + lq * 8];
#pragma unroll
            for (int ct = 0; ct < 4; ++ct)
                bfr[ct] = *(const short8*)&Bs[(wcol + ct * 16 + lm) * LDK + lq * 8];
#pragma unroll
            for (int rt = 0; rt < 2; ++rt)
#pragma unroll
                for (int ct = 0; ct < 4; ++ct)
                    acc[rt][ct] = __builtin_amdgcn_mfma_f32_16x16x32_bf16(
                        af[rt], bfr[ct], acc[rt][ct], 0, 0, 0);
            // all ds_reads are consumed by the MFMAs above (compiler-inserted
            // lgkm waits), so reaching this barrier implies reads completed.
            bar_only();

            a0 = na0; a1 = na1; wb0 = nb0; wb1 = nb1;
        }

        // epilogue: D row = lq*4 + r, col = lm
#pragma unroll
        for (int ct = 0; ct < 4; ++ct) {
            int gcol = wcol + ct * 16 + lm;
            float bv = bias[gcol];
#pragma unroll
            for (int rt = 0; rt < 2; ++rt) {
#pragma unroll
                for (int r = 0; r < 4; ++r) {
                    int grow = m0 + wrow + rt * 16 + lq * 4 + r;
                    if (grow < N_NODES)
                        linbf[(size_t)grow * OUT_CH + gcol] = f2bf(acc[rt][ct][r] + bv);
                }
            }
        }
    } else {
        // ================= bucket-scatter part =================
        // packed record: src (16b) | (dst&127)<<16 (7b) | (dst>>7)<<23 (9b)
        int* lhist       = (int*)smem;             // 1564 B
        int* lscan       = (int*)(smem + 1568);    // 1564 B
        int* lbase       = (int*)(smem + 3136);    // 1564 B
        unsigned* staged = (unsigned*)(smem + 4704); // 8192 B

        const int blk = blockIdx.x - NGEMM;
        const int e0  = blk * L1_CHUNK;
        const int total = min(L1_CHUNK, N_EDGES - e0);

        for (int i = tid; i < NB; i += 256) lhist[i] = 0;
        __syncthreads();

        unsigned mypk[8];
        int myr[8];
        int myb[8];
#pragma unroll
        for (int j = 0; j < 8; ++j) {
            int i = tid + j * 256;
            myb[j] = -1;
            if (i < total) {
                unsigned d = (unsigned)dst[e0 + i];
                unsigned s = (unsigned)src[e0 + i];
                int b = (int)(d >> 7);
                myb[j] = b;
                mypk[j] = s | ((d & 127u) << 16) | ((unsigned)b << 23);
                myr[j] = atomicAdd(&lhist[b], 1);
            }
        }
        __syncthreads();

        // exclusive scan lhist -> lscan (wave 0, 7 chunks of 64)
        if (tid < 64) {
            int carry = 0;
            for (int c = 0; c < NB; c += 64) {
                int idx = c + tid;
                int v = (idx < NB) ? lhist[idx] : 0;
                int incl = v;
#pragma unroll
                for (int s = 1; s < 64; s <<= 1) {
                    int t = __shfl_up(incl, s, 64);
                    if (tid >= s) incl += t;
                }
                if (idx < NB) lscan[idx] = carry + incl - v;
                carry += __shfl(incl, 63, 64);
            }
        }
        __syncthreads();

        // reserve global space (one atomic per nonempty bucket) + stage locally
        for (int bkt = tid; bkt < NB; bkt += 256) {
            int c = lhist[bkt];
            lbase[bkt] = c ? atomicAdd(&bcnt[bkt], c) : 0;
        }
#pragma unroll
        for (int j = 0; j < 8; ++j) {
            if (myb[j] >= 0)
                staged[lscan[myb[j]] + myr[j]] = mypk[j];
        }
        __syncthreads();

        // write out: bucket-grouped runs -> mostly-contiguous global stores
        for (int p = tid; p < total; p += 256) {
            unsigned r = staged[p];
            int b = (int)(r >> 23);
            int gpos = lbase[b] + (p - lscan[b]);
            if (gpos < CAP)
                rec[(size_t)b * CAP + gpos] = r;
        }
    }
}

// ---------- fused: fine sort (LDS) + gather-mean for 128 nodes/block -----
// 1024 threads: 16 waves/block for latency hiding on the random-row gather.
// R6: gather unroll deepened 4 -> 8 (8 outstanding 16B loads per lane) for
// more MLP in the latency-bound random linbf-row reads.
#define FG_THR 1024
__global__ __launch_bounds__(FG_THR) void fine_gather(const int* __restrict__ bcnt,
                                                      const unsigned* __restrict__ rec,
                                                      const short* __restrict__ linbf,
                                                      float* __restrict__ out) {
    __shared__ unsigned srec[CAP];          // 12288 B
    __shared__ unsigned short ssrc[CAP];    // 6144 B
    __shared__ int fh[128], fo[128], fc[128];

    const int b = blockIdx.x;
    const int tid = threadIdx.x;
    const int cnt = min(bcnt[b], CAP);

    // load records, histogram fine node (dst & 127)
    for (int i = tid; i < cnt; i += FG_THR)
        srec[i] = rec[(size_t)b * CAP + i];
    if (tid < 128) fh[tid] = 0;
    __syncthreads();

    for (int i = tid; i < cnt; i += FG_THR)
        atomicAdd(&fh[(srec[i] >> 16) & 127u], 1);
    __syncthreads();

    // exclusive scan of 128 counters (wave 0)
    if (tid < 64) {
        int carry = 0;
        for (int c = 0; c < 128; c += 64) {
            int v = fh[c + tid];
            int incl = v;
#pragma unroll
            for (int s = 1; s < 64; s <<= 1) {
                int t = __shfl_up(incl, s, 64);
                if (tid >= s) incl += t;
            }
            fo[c + tid] = carry + incl - v;
            carry += __shfl(incl, 63, 64);
        }
    }
    __syncthreads();
    if (tid < 128) fc[tid] = fo[tid];
    __syncthreads();

    // sorted scatter into LDS ssrc
    for (int i = tid; i < cnt; i += FG_THR) {
        unsigned r = srec[i];
        int p = atomicAdd(&fc[(r >> 16) & 127u], 1);
        ssrc[p] = (unsigned short)(r & 0xffffu);
    }
    __syncthreads();

    // gather phase: 16 lanes per node, 64 nodes in flight, 2 rounds
    const int l = tid & 15;
#pragma unroll 1
    for (int g = 0; g < 2; ++g) {
        int nl = g * 64 + (tid >> 4);          // local node 0..127
        int n = b * 128 + nl;
        if (n >= N_NODES) continue;
        const int beg = fo[nl];
        const int deg = fh[nl];
        const int end = beg + deg;

        float a[8];
#pragma unroll
        for (int j = 0; j < 8; ++j) a[j] = 0.0f;

        int i = beg;
        for (; i + 7 < end; i += 8) {
            uint4 u[8];
#pragma unroll
            for (int e = 0; e < 8; ++e) {
                int s = ssrc[i + e];
                u[e] = *(const uint4*)&linbf[(size_t)s * OUT_CH + l * 8];
            }
#pragma unroll
            for (int e = 0; e < 8; ++e) {
                const unsigned* p = (const unsigned*)&u[e];
#pragma unroll
                for (int j = 0; j < 4; ++j) {
                    a[2*j]   += __uint_as_float(p[j] << 16);
                    a[2*j+1] += __uint_as_float(p[j] & 0xffff0000u);
                }
            }
        }
        for (; i + 3 < end; i += 4) {
            uint4 u[4];
#pragma unroll
            for (int e = 0; e < 4; ++e) {
                int s = ssrc[i + e];
                u[e] = *(const uint4*)&linbf[(size_t)s * OUT_CH + l * 8];
            }
#pragma unroll
            for (int e = 0; e < 4; ++e) {
                const unsigned* p = (const unsigned*)&u[e];
#pragma unroll
                for (int j = 0; j < 4; ++j) {
                    a[2*j]   += __uint_as_float(p[j] << 16);
                    a[2*j+1] += __uint_as_float(p[j] & 0xffff0000u);
                }
            }
        }
        for (; i < end; ++i) {
            int s = ssrc[i];
            uint4 u0 = *(const uint4*)&linbf[(size_t)s * OUT_CH + l * 8];
            const unsigned* p0 = (const unsigned*)&u0;
#pragma unroll
            for (int j = 0; j < 4; ++j) {
                a[2*j]   += __uint_as_float(p0[j] << 16);
                a[2*j+1] += __uint_as_float(p0[j] & 0xffff0000u);
            }
        }
        float inv = 1.0f / (float)(deg > 1 ? deg : 1);
        float4 o0, o1;
        o0.x = a[0]*inv; o0.y = a[1]*inv; o0.z = a[2]*inv; o0.w = a[3]*inv;
        o1.x = a[4]*inv; o1.y = a[5]*inv; o1.z = a[6]*inv; o1.w = a[7]*inv;
        float* op = &out[(size_t)n * OUT_CH + l * 8];
        ((float4*)op)[0] = o0;
        ((float4*)op)[1] = o1;
    }
}

extern "C" void kernel_launch(void* const* d_in, const int* in_sizes, int n_in,
                              void* d_out, int out_size, void* d_ws, size_t ws_size,
                              hipStream_t stream) {
    const float* x  = (const float*)d_in[0];
    const int*   ei = (const int*)d_in[1];     // [2][E]: src then dst
    const float* W  = (const float*)d_in[2];
    const float* b  = (const float*)d_in[3];
    float* out = (float*)d_out;

    const int* src = ei;
    const int* dst = ei + N_EDGES;

    // workspace: linbf 12.8MB | Wbf 64KB | rec 4.8MB | bcnt
    char* ws = (char*)d_ws;
    short*    linbf = (short*)ws;    ws += ((size_t)N_NODES * OUT_CH * sizeof(short) + 255) & ~255ull;
    short*    Wbf   = (short*)ws;    ws += ((size_t)IN_CH * OUT_CH * sizeof(short) + 255) & ~255ull;
    unsigned* rec   = (unsigned*)ws; ws += ((size_t)NB * CAP * sizeof(unsigned) + 255) & ~255ull;
    int*      bcnt  = (int*)ws;

    convert_w<<<16, 256, 0, stream>>>(W, Wbf, bcnt);
    gemm_bucket<<<NGEMM + NBUK, 256, 0, stream>>>(x, Wbf, b, linbf, src, dst, bcnt, rec);
    fine_gather<<<NB, FG_THR, 0, stream>>>(bcnt, rec, linbf, out);
}

// Round 7
// 143.768 us; speedup vs baseline: 2.4002x; 1.0199x over previous
//
#include <hip/hip_runtime.h>

#define N_NODES 50000
#define N_EDGES 800000
#define IN_CH   256
#define OUT_CH  128

#define NB        391          // coarse buckets of 128 nodes: ceil(50000/128)
#define CAP       3072         // record capacity per bucket (mean 2048, sd ~45)
#define L1_CHUNK  2048
#define NBUK      ((N_EDGES + L1_CHUNK - 1) / L1_CHUNK)   // 391 bucket chunks
#define GBM       64
#define NGEMM     ((N_NODES + GBM - 1) / GBM)             // 782 gemm tiles
#define GBK 32
#define NKIT (IN_CH / GBK)     // 8 K-iterations
#define LDK 40   // padded A-row length (bf16 elems); 80B stride keeps 16B align

#define AS1 __attribute__((address_space(1)))
#define AS3 __attribute__((address_space(3)))

typedef __attribute__((ext_vector_type(8))) short short8;   // 8 bf16 (4 VGPRs)
typedef __attribute__((ext_vector_type(4))) float f32x4;

__device__ __forceinline__ short f2bf(float f) {
    unsigned u = __float_as_uint(f);
    unsigned r = (u + 0x7fffu + ((u >> 16) & 1u)) >> 16;    // RNE
    return (short)r;
}

// ------------- one-time: W fp32 -> bf16 K-TILED+SWIZZLED, zero bcnt ------
// Layout: WbfT[kk][r][s'] with kk=k0/32 (8 tiles of 8KB), r=out-ch row
// 0..127, s' = 16B-unit slot = s ^ ((r>>1)&3). Baking the XOR swizzle into
// storage lets gemm stage B with LINEAR global_load_lds (dest = wave base
// + lane*16) while the fragment ds_read applies the same XOR: 16
// consecutive rows then spread 2 lanes/bank (free, m136) instead of the
// 8-way conflict a naive [128][32] layout gives at 64B row stride.
__global__ __launch_bounds__(256) void convert_w(const float* __restrict__ W,
                                                 short* __restrict__ WbfT,
                                                 int* __restrict__ bcnt) {
    int t = blockIdx.x * 256 + threadIdx.x;       // 4096 units of 8 floats
    const float* wp = W + t * 8;
    float4 v0 = ((const float4*)wp)[0];
    float4 v1 = ((const float4*)wp)[1];
    short8 s;
    s[0]=f2bf(v0.x); s[1]=f2bf(v0.y); s[2]=f2bf(v0.z); s[3]=f2bf(v0.w);
    s[4]=f2bf(v1.x); s[5]=f2bf(v1.y); s[6]=f2bf(v1.z); s[7]=f2bf(v1.w);
    int r  = t >> 5;               // out-ch row 0..127
    int g  = t & 31;               // k-unit 0..31
    int kk = g >> 2;               // K-tile 0..7
    int sl = g & 3;                // logical slot within tile row
    int s2 = sl ^ ((r >> 1) & 3);  // swizzled physical slot
    *(short8*)&WbfT[(size_t)kk * 4096 + r * 32 + s2 * 8] = s;
    if (t < NB) bcnt[t] = 0;
}

// ---------------- fused: MFMA GEMM (blocks 0..781) + edge bucketing ------
// R7: B staged via global_load_lds width=16 (guide Common-mistake #1):
// no VGPR round-trip, no ds_writes on the B path. __syncthreads' vmcnt
// drain is what completes the DMA — required, not overhead. A keeps the
// reg+f2bf path (fp32 input needs conversion) into the padded As tile.
__global__ __launch_bounds__(256) void gemm_bucket(const float* __restrict__ x,
                                                   const short* __restrict__ WbfT,
                                                   const float* __restrict__ bias,
                                                   short* __restrict__ linbf,
                                                   const int* __restrict__ src,
                                                   const int* __restrict__ dst,
                                                   int* __restrict__ bcnt,
                                                   unsigned* __restrict__ rec) {
    __shared__ __align__(16) char smem[15360];
    const int tid = threadIdx.x;

    if (blockIdx.x < NGEMM) {
        // ================= GEMM part =================
        short* As = (short*)smem;              // 5120 B: [64][LDK] padded
        unsigned short* Bs = (unsigned short*)(smem + 5120); // 8192 B linear

        const int m0  = blockIdx.x * GBM;
        const int w    = tid >> 6;
        const int lane = tid & 63;
        const int lm   = lane & 15;
        const int lq   = lane >> 4;
        const int wrow = (w >> 1) * 32;
        const int wcol = (w & 1) * 64;

        f32x4 acc[2][4];
#pragma unroll
        for (int i = 0; i < 2; ++i)
#pragma unroll
            for (int j = 0; j < 4; ++j) acc[i][j] = (f32x4)(0.0f);

        const int arow = tid >> 2;        // A staging row (0..63)
        const int aq   = tid & 3;         // which 8-k group
        const bool arowok = (m0 + arow < N_NODES);
        const float* xp = x + (size_t)(m0 + arow) * IN_CH + aq * 8;

        const unsigned short* wt = (const unsigned short*)WbfT;
        unsigned short* bdst = Bs + (size_t)(tid & ~63) * 8;   // wave-uniform

        for (int kk = 0; kk < NKIT; ++kk) {
            // stage A: 64 rows x 32 k, fp32 -> bf16 (32 B / thread)
            {
                float4 v0 = make_float4(0.f,0.f,0.f,0.f), v1 = v0;
                if (arowok) {
                    const float* xq = xp + kk * GBK;
                    v0 = ((const float4*)xq)[0];
                    v1 = ((const float4*)xq)[1];
                }
                short8 s;
                s[0]=f2bf(v0.x); s[1]=f2bf(v0.y); s[2]=f2bf(v0.z); s[3]=f2bf(v0.w);
                s[4]=f2bf(v1.x); s[5]=f2bf(v1.y); s[6]=f2bf(v1.z); s[7]=f2bf(v1.w);
                *(short8*)&As[arow * LDK + aq * 8] = s;
            }
            // stage B: 8KB tile via 2x global_load_lds (linear dest,
            // swizzle pre-baked in WbfT storage order)
            {
                const unsigned short* wsrc = wt + (size_t)kk * 4096 + tid * 8;
                __builtin_amdgcn_global_load_lds((const AS1 void*)wsrc,
                                                 (AS3 void*)bdst, 16, 0, 0);
                __builtin_amdgcn_global_load_lds((const AS1 void*)(wsrc + 2048),
                                                 (AS3 void*)(bdst + 2048), 16, 0, 0);
            }
            __syncthreads();   // drains vmcnt: completes the B DMA + A writes

            short8 af[2], bfr[4];
#pragma unroll
            for (int rt = 0; rt < 2; ++rt)
                af[rt] = *(const short8*)&As[(wrow + rt * 16 + lm) * LDK + lq * 8];
#pragma unroll
            for (int ct = 0; ct < 4; ++ct) {
                int r2 = wcol + ct * 16 + lm;
                bfr[ct] = *(const short8*)&Bs[r2 * 32 + ((lq ^ ((r2 >> 1) & 3)) * 8)];
            }
#pragma unroll
            for (int rt = 0; rt < 2; ++rt)
#pragma unroll
                for (int ct = 0; ct < 4; ++ct)
                    acc[rt][ct] = __builtin_amdgcn_mfma_f32_16x16x32_bf16(
                        af[rt], bfr[ct], acc[rt][ct], 0, 0, 0);
            __syncthreads();
        }

        // epilogue: D row = lq*4 + r, col = lm
#pragma unroll
        for (int ct = 0; ct < 4; ++ct) {
            int gcol = wcol + ct * 16 + lm;
            float bv = bias[gcol];
#pragma unroll
            for (int rt = 0; rt < 2; ++rt) {
#pragma unroll
                for (int r = 0; r < 4; ++r) {
                    int grow = m0 + wrow + rt * 16 + lq * 4 + r;
                    if (grow < N_NODES)
                        linbf[(size_t)grow * OUT_CH + gcol] = f2bf(acc[rt][ct][r] + bv);
                }
            }
        }
    } else {
        // ================= bucket-scatter part =================
        // packed record: src (16b) | (dst&127)<<16 (7b) | (dst>>7)<<23 (9b)
        int* lhist       = (int*)smem;             // 1564 B
        int* lscan       = (int*)(smem + 1568);    // 1564 B
        int* lbase       = (int*)(smem + 3136);    // 1564 B
        unsigned* staged = (unsigned*)(smem + 4704); // 8192 B

        const int blk = blockIdx.x - NGEMM;
        const int e0  = blk * L1_CHUNK;
        const int total = min(L1_CHUNK, N_EDGES - e0);

        for (int i = tid; i < NB; i += 256) lhist[i] = 0;
        __syncthreads();

        unsigned mypk[8];
        int myr[8];
        int myb[8];
#pragma unroll
        for (int j = 0; j < 8; ++j) {
            int i = tid + j * 256;
            myb[j] = -1;
            if (i < total) {
                unsigned d = (unsigned)dst[e0 + i];
                unsigned s = (unsigned)src[e0 + i];
                int b = (int)(d >> 7);
                myb[j] = b;
                mypk[j] = s | ((d & 127u) << 16) | ((unsigned)b << 23);
                myr[j] = atomicAdd(&lhist[b], 1);
            }
        }
        __syncthreads();

        // exclusive scan lhist -> lscan (wave 0, 7 chunks of 64)
        if (tid < 64) {
            int carry = 0;
            for (int c = 0; c < NB; c += 64) {
                int idx = c + tid;
                int v = (idx < NB) ? lhist[idx] : 0;
                int incl = v;
#pragma unroll
                for (int s = 1; s < 64; s <<= 1) {
                    int t = __shfl_up(incl, s, 64);
                    if (tid >= s) incl += t;
                }
                if (idx < NB) lscan[idx] = carry + incl - v;
                carry += __shfl(incl, 63, 64);
            }
        }
        __syncthreads();

        // reserve global space (one atomic per nonempty bucket) + stage locally
        for (int bkt = tid; bkt < NB; bkt += 256) {
            int c = lhist[bkt];
            lbase[bkt] = c ? atomicAdd(&bcnt[bkt], c) : 0;
        }
#pragma unroll
        for (int j = 0; j < 8; ++j) {
            if (myb[j] >= 0)
                staged[lscan[myb[j]] + myr[j]] = mypk[j];
        }
        __syncthreads();

        // write out: bucket-grouped runs -> mostly-contiguous global stores
        for (int p = tid; p < total; p += 256) {
            unsigned r = staged[p];
            int b = (int)(r >> 23);
            int gpos = lbase[b] + (p - lscan[b]);
            if (gpos < CAP)
                rec[(size_t)b * CAP + gpos] = r;
        }
    }
}

// ---------- fused: fine sort (LDS) + gather-mean for 128 nodes/block -----
// 1024 threads: 16 waves/block. R0-exact version (4-deep unroll: u[4] =
// 16 VGPR keeps the kernel under the 64-VGPR 2-blocks/CU threshold; R6's
// 8-deep showed no gain, likely halving occupancy).
#define FG_THR 1024
__global__ __launch_bounds__(FG_THR) void fine_gather(const int* __restrict__ bcnt,
                                                      const unsigned* __restrict__ rec,
                                                      const short* __restrict__ linbf,
                                                      float* __restrict__ out) {
    __shared__ unsigned srec[CAP];          // 12288 B
    __shared__ unsigned short ssrc[CAP];    // 6144 B
    __shared__ int fh[128], fo[128], fc[128];

    const int b = blockIdx.x;
    const int tid = threadIdx.x;
    const int cnt = min(bcnt[b], CAP);

    // load records, histogram fine node (dst & 127)
    for (int i = tid; i < cnt; i += FG_THR)
        srec[i] = rec[(size_t)b * CAP + i];
    if (tid < 128) fh[tid] = 0;
    __syncthreads();

    for (int i = tid; i < cnt; i += FG_THR)
        atomicAdd(&fh[(srec[i] >> 16) & 127u], 1);
    __syncthreads();

    // exclusive scan of 128 counters (wave 0)
    if (tid < 64) {
        int carry = 0;
        for (int c = 0; c < 128; c += 64) {
            int v = fh[c + tid];
            int incl = v;
#pragma unroll
            for (int s = 1; s < 64; s <<= 1) {
                int t = __shfl_up(incl, s, 64);
                if (tid >= s) incl += t;
            }
            fo[c + tid] = carry + incl - v;
            carry += __shfl(incl, 63, 64);
        }
    }
    __syncthreads();
    if (tid < 128) fc[tid] = fo[tid];
    __syncthreads();

    // sorted scatter into LDS ssrc
    for (int i = tid; i < cnt; i += FG_THR) {
        unsigned r = srec[i];
        int p = atomicAdd(&fc[(r >> 16) & 127u], 1);
        ssrc[p] = (unsigned short)(r & 0xffffu);
    }
    __syncthreads();

    // gather phase: 16 lanes per node, 64 nodes in flight, 2 rounds
    const int l = tid & 15;
#pragma unroll 1
    for (int g = 0; g < 2; ++g) {
        int nl = g * 64 + (tid >> 4);          // local node 0..127
        int n = b * 128 + nl;
        if (n >= N_NODES) continue;
        const int beg = fo[nl];
        const int deg = fh[nl];
        const int end = beg + deg;

        float a[8];
#pragma unroll
        for (int j = 0; j < 8; ++j) a[j] = 0.0f;

        int i = beg;
        for (; i + 3 < end; i += 4) {
            uint4 u[4];
#pragma unroll
            for (int e = 0; e < 4; ++e) {
                int s = ssrc[i + e];
                u[e] = *(const uint4*)&linbf[(size_t)s * OUT_CH + l * 8];
            }
#pragma unroll
            for (int e = 0; e < 4; ++e) {
                const unsigned* p = (const unsigned*)&u[e];
#pragma unroll
                for (int j = 0; j < 4; ++j) {
                    a[2*j]   += __uint_as_float(p[j] << 16);
                    a[2*j+1] += __uint_as_float(p[j] & 0xffff0000u);
                }
            }
        }
        for (; i < end; ++i) {
            int s = ssrc[i];
            uint4 u0 = *(const uint4*)&linbf[(size_t)s * OUT_CH + l * 8];
            const unsigned* p0 = (const unsigned*)&u0;
#pragma unroll
            for (int j = 0; j < 4; ++j) {
                a[2*j]   += __uint_as_float(p0[j] << 16);
                a[2*j+1] += __uint_as_float(p0[j] & 0xffff0000u);
            }
        }
        float inv = 1.0f / (float)(deg > 1 ? deg : 1);
        float4 o0, o1;
        o0.x = a[0]*inv; o0.y = a[1]*inv; o0.z = a[2]*inv; o0.w = a[3]*inv;
        o1.x = a[4]*inv; o1.y = a[5]*inv; o1.z = a[6]*inv; o1.w = a[7]*inv;
        float* op = &out[(size_t)n * OUT_CH + l * 8];
        ((float4*)op)[0] = o0;
        ((float4*)op)[1] = o1;
    }
}

extern "C" void kernel_launch(void* const* d_in, const int* in_sizes, int n_in,
                              void* d_out, int out_size, void* d_ws, size_t ws_size,
                              hipStream_t stream) {
    const float* x  = (const float*)d_in[0];
    const int*   ei = (const int*)d_in[1];     // [2][E]: src then dst
    const float* W  = (const float*)d_in[2];
    const float* b  = (const float*)d_in[3];
    float* out = (float*)d_out;

    const int* src = ei;
    const int* dst = ei + N_EDGES;

    // workspace: linbf 12.8MB | WbfT 64KB | rec 4.8MB | bcnt
    char* ws = (char*)d_ws;
    short*    linbf = (short*)ws;    ws += ((size_t)N_NODES * OUT_CH * sizeof(short) + 255) & ~255ull;
    short*    WbfT  = (short*)ws;    ws += ((size_t)IN_CH * OUT_CH * sizeof(short) + 255) & ~255ull;
    unsigned* rec   = (unsigned*)ws; ws += ((size_t)NB * CAP * sizeof(unsigned) + 255) & ~255ull;
    int*      bcnt  = (int*)ws;

    convert_w<<<16, 256, 0, stream>>>(W, WbfT, bcnt);
    gemm_bucket<<<NGEMM + NBUK, 256, 0, stream>>>(x, WbfT, b, linbf, src, dst, bcnt, rec);
    fine_gather<<<NB, FG_THR, 0, stream>>>(bcnt, rec, linbf, out);
}

// Round 9
// 142.023 us; speedup vs baseline: 2.4297x; 1.0123x over previous
//
#include <hip/hip_runtime.h>

#define N_NODES 50000
#define N_EDGES 800000
#define IN_CH   256
#define OUT_CH  128

#define NB        391          // coarse buckets of 128 nodes: ceil(50000/128)
#define CAP       3072         // record capacity per bucket (mean 2048, sd ~45)
#define L1_CHUNK  2048
#define GBM       64
#define NGEMM     ((N_NODES + GBM - 1) / GBM)             // 782 gemm blocks

typedef __attribute__((ext_vector_type(8))) short short8;   // 8 bf16 (4 VGPRs)
typedef __attribute__((ext_vector_type(4))) float f32x4;

__device__ __forceinline__ short f2bf(float f) {
    unsigned u = __float_as_uint(f);
    unsigned r = (u + 0x7fffu + ((u >> 16) & 1u)) >> 16;    // RNE
    return (short)r;
}

// ------------- one-time: W fp32 -> bf16, zero bcnt -----------------------
__global__ __launch_bounds__(256) void convert_w(const float* __restrict__ W,
                                                 short* __restrict__ Wbf,
                                                 int* __restrict__ bcnt) {
    int t = blockIdx.x * 256 + threadIdx.x;       // 4096 threads, 8 floats each
    const float* wp = W + t * 8;
    float4 v0 = ((const float4*)wp)[0];
    float4 v1 = ((const float4*)wp)[1];
    short8 s;
    s[0]=f2bf(v0.x); s[1]=f2bf(v0.y); s[2]=f2bf(v0.z); s[3]=f2bf(v0.w);
    s[4]=f2bf(v1.x); s[5]=f2bf(v1.y); s[6]=f2bf(v1.z); s[7]=f2bf(v1.w);
    *(short8*)&Wbf[t * 8] = s;
    if (t < NB) bcnt[t] = 0;
}

// ---------------- fused: MFMA GEMM (blocks 0..781) + edge bucketing ------
// GEMM tile 64x128: 782 blocks -> ~4.6 blocks/CU so the per-iter HBM
// A-load latency hides across blocks (128-tile gave only 1.5 blocks/CU).
// R1-R7 post-mortems: quarter-gather (R1 +4us), coop fusion (R3 +200us,
// ~52us coop-launch overhead), inline W-convert (R5 +6us), K-prefetch
// pipeline + raw lgkm barriers + 8-deep gather (R6 null), global_load_lds
// B-staging with pre-swizzled Wbf (R7 null) -- this R0 configuration is
// the measured optimum; total is ~92us fixed harness cost + ~49us of
// kernels sitting within ~1.4x of their HBM/L3 memory floors.
#define GBK 32
#define LDK 40   // padded row length (bf16 elems); 80B stride keeps 16B align
__global__ __launch_bounds__(256) void gemm_bucket(const float* __restrict__ x,
                                                   const short* __restrict__ Wbf,
                                                   const float* __restrict__ bias,
                                                   short* __restrict__ linbf,
                                                   const int* __restrict__ src,
                                                   const int* __restrict__ dst,
                                                   int* __restrict__ bcnt,
                                                   unsigned* __restrict__ rec) {
    __shared__ __align__(16) char smem[15360];
    const int tid = threadIdx.x;

    if (blockIdx.x < NGEMM) {
        // ================= GEMM part =================
        short* As = (short*)smem;            // 5120 B:  [m][k] tile (64 x 32)
        short* Bs = (short*)(smem + 5120);   // 10240 B: [n][k] tile (128 x 32)

        const int m0  = blockIdx.x * GBM;
        const int w    = tid >> 6;
        const int lane = tid & 63;
        const int lm   = lane & 15;
        const int lq   = lane >> 4;
        const int wrow = (w >> 1) * 32;
        const int wcol = (w & 1) * 64;

        f32x4 acc[2][4];
#pragma unroll
        for (int i = 0; i < 2; ++i)
#pragma unroll
            for (int j = 0; j < 4; ++j) acc[i][j] = (f32x4)(0.0f);

        const int arow = tid >> 2;        // A staging row (0..63)
        const int aq   = tid & 3;         // which 8-k group
        const int brow = tid >> 1;        // B staging row (0..127)
        const int bhalf = tid & 1;        // which 16-k half

        for (int k0 = 0; k0 < IN_CH; k0 += GBK) {
            // stage A: 64 rows x 32 k, fp32 -> bf16 (32 B / thread)
            {
                float4 v0 = make_float4(0.f,0.f,0.f,0.f), v1 = v0;
                if (m0 + arow < N_NODES) {
                    const float* xp = x + (size_t)(m0 + arow) * IN_CH + k0 + aq * 8;
                    v0 = ((const float4*)xp)[0];
                    v1 = ((const float4*)xp)[1];
                }
                short8 s;
                s[0]=f2bf(v0.x); s[1]=f2bf(v0.y); s[2]=f2bf(v0.z); s[3]=f2bf(v0.w);
                s[4]=f2bf(v1.x); s[5]=f2bf(v1.y); s[6]=f2bf(v1.z); s[7]=f2bf(v1.w);
                *(short8*)&As[arow * LDK + aq * 8] = s;
            }
            // stage B: 128 n x 32 k (pre-converted bf16, straight copy)
            {
                const short* wp = Wbf + (size_t)brow * IN_CH + k0 + bhalf * 16;
                *(short8*)&Bs[brow * LDK + bhalf * 16]     = ((const short8*)wp)[0];
                *(short8*)&Bs[brow * LDK + bhalf * 16 + 8] = ((const short8*)wp)[1];
            }
            __syncthreads();

            short8 af[2], bfr[4];
#pragma unroll
            for (int rt = 0; rt < 2; ++rt)
                af[rt] = *(const short8*)&As[(wrow + rt * 16 + lm) * LDK + lq * 8];
#pragma unroll
            for (int ct = 0; ct < 4; ++ct)
                bfr[ct] = *(const short8*)&Bs[(wcol + ct * 16 + lm) * LDK + lq * 8];
#pragma unroll
            for (int rt = 0; rt < 2; ++rt)
#pragma unroll
                for (int ct = 0; ct < 4; ++ct)
                    acc[rt][ct] = __builtin_amdgcn_mfma_f32_16x16x32_bf16(
                        af[rt], bfr[ct], acc[rt][ct], 0, 0, 0);
            __syncthreads();
        }

        // epilogue: D row = lq*4 + r, col = lm
#pragma unroll
        for (int ct = 0; ct < 4; ++ct) {
            int gcol = wcol + ct * 16 + lm;
            float bv = bias[gcol];
#pragma unroll
            for (int rt = 0; rt < 2; ++rt) {
#pragma unroll
                for (int r = 0; r < 4; ++r) {
                    int grow = m0 + wrow + rt * 16 + lq * 4 + r;
                    if (grow < N_NODES)
                        linbf[(size_t)grow * OUT_CH + gcol] = f2bf(acc[rt][ct][r] + bv);
                }
            }
        }
    } else {
        // ================= bucket-scatter part =================
        // packed record: src (16b) | (dst&127)<<16 (7b) | (dst>>7)<<23 (9b)
        int* lhist       = (int*)smem;             // 1564 B
        int* lscan       = (int*)(smem + 1568);    // 1564 B
        int* lbase       = (int*)(smem + 3136);    // 1564 B
        unsigned* staged = (unsigned*)(smem + 4704); // 8192 B

        const int blk = blockIdx.x - NGEMM;
        const int e0  = blk * L1_CHUNK;
        const int total = min(L1_CHUNK, N_EDGES - e0);

        for (int i = tid; i < NB; i += 256) lhist[i] = 0;
        __syncthreads();

        unsigned mypk[8];
        int myr[8];
        int myb[8];
#pragma unroll
        for (int j = 0; j < 8; ++j) {
            int i = tid + j * 256;
            myb[j] = -1;
            if (i < total) {
                unsigned d = (unsigned)dst[e0 + i];
                unsigned s = (unsigned)src[e0 + i];
                int b = (int)(d >> 7);
                myb[j] = b;
                mypk[j] = s | ((d & 127u) << 16) | ((unsigned)b << 23);
                myr[j] = atomicAdd(&lhist[b], 1);
            }
        }
        __syncthreads();

        // exclusive scan lhist -> lscan (wave 0, 7 chunks of 64)
        if (tid < 64) {
            int carry = 0;
            for (int c = 0; c < NB; c += 64) {
                int idx = c + tid;
                int v = (idx < NB) ? lhist[idx] : 0;
                int incl = v;
#pragma unroll
                for (int s = 1; s < 64; s <<= 1) {
                    int t = __shfl_up(incl, s, 64);
                    if (tid >= s) incl += t;
                }
                if (idx < NB) lscan[idx] = carry + incl - v;
                carry += __shfl(incl, 63, 64);
            }
        }
        __syncthreads();

        // reserve global space (one atomic per nonempty bucket) + stage locally
        for (int bkt = tid; bkt < NB; bkt += 256) {
            int c = lhist[bkt];
            lbase[bkt] = c ? atomicAdd(&bcnt[bkt], c) : 0;
        }
#pragma unroll
        for (int j = 0; j < 8; ++j) {
            if (myb[j] >= 0)
                staged[lscan[myb[j]] + myr[j]] = mypk[j];
        }
        __syncthreads();

        // write out: bucket-grouped runs -> mostly-contiguous global stores
        for (int p = tid; p < total; p += 256) {
            unsigned r = staged[p];
            int b = (int)(r >> 23);
            int gpos = lbase[b] + (p - lscan[b]);
            if (gpos < CAP)
                rec[(size_t)b * CAP + gpos] = r;
        }
    }
}

// ---------- fused: fine sort (LDS) + gather-mean for 128 nodes/block -----
// 1024 threads: 16 waves/block for latency hiding on the random-row gather.
#define FG_THR 1024
__global__ __launch_bounds__(FG_THR) void fine_gather(const int* __restrict__ bcnt,
                                                      const unsigned* __restrict__ rec,
                                                      const short* __restrict__ linbf,
                                                      float* __restrict__ out) {
    __shared__ unsigned srec[CAP];          // 12288 B
    __shared__ unsigned short ssrc[CAP];    // 6144 B
    __shared__ int fh[128], fo[128], fc[128];

    const int b = blockIdx.x;
    const int tid = threadIdx.x;
    const int cnt = min(bcnt[b], CAP);

    // load records, histogram fine node (dst & 127)
    for (int i = tid; i < cnt; i += FG_THR)
        srec[i] = rec[(size_t)b * CAP + i];
    if (tid < 128) fh[tid] = 0;
    __syncthreads();

    for (int i = tid; i < cnt; i += FG_THR)
        atomicAdd(&fh[(srec[i] >> 16) & 127u], 1);
    __syncthreads();

    // exclusive scan of 128 counters (wave 0)
    if (tid < 64) {
        int carry = 0;
        for (int c = 0; c < 128; c += 64) {
            int v = fh[c + tid];
            int incl = v;
#pragma unroll
            for (int s = 1; s < 64; s <<= 1) {
                int t = __shfl_up(incl, s, 64);
                if (tid >= s) incl += t;
            }
            fo[c + tid] = carry + incl - v;
            carry += __shfl(incl, 63, 64);
        }
    }
    __syncthreads();
    if (tid < 128) fc[tid] = fo[tid];
    __syncthreads();

    // sorted scatter into LDS ssrc
    for (int i = tid; i < cnt; i += FG_THR) {
        unsigned r = srec[i];
        int p = atomicAdd(&fc[(r >> 16) & 127u], 1);
        ssrc[p] = (unsigned short)(r & 0xffffu);
    }
    __syncthreads();

    // gather phase: 16 lanes per node, 64 nodes in flight, 2 rounds
    const int l = tid & 15;
#pragma unroll 1
    for (int g = 0; g < 2; ++g) {
        int nl = g * 64 + (tid >> 4);          // local node 0..127
        int n = b * 128 + nl;
        if (n >= N_NODES) continue;
        const int beg = fo[nl];
        const int deg = fh[nl];
        const int end = beg + deg;

        float a[8];
#pragma unroll
        for (int j = 0; j < 8; ++j) a[j] = 0.0f;

        int i = beg;
        for (; i + 3 < end; i += 4) {
            uint4 u[4];
#pragma unroll
            for (int e = 0; e < 4; ++e) {
                int s = ssrc[i + e];
                u[e] = *(const uint4*)&linbf[(size_t)s * OUT_CH + l * 8];
            }
#pragma unroll
            for (int e = 0; e < 4; ++e) {
                const unsigned* p = (const unsigned*)&u[e];
#pragma unroll
                for (int j = 0; j < 4; ++j) {
                    a[2*j]   += __uint_as_float(p[j] << 16);
                    a[2*j+1] += __uint_as_float(p[j] & 0xffff0000u);
                }
            }
        }
        for (; i < end; ++i) {
            int s = ssrc[i];
            uint4 u0 = *(const uint4*)&linbf[(size_t)s * OUT_CH + l * 8];
            const unsigned* p0 = (const unsigned*)&u0;
#pragma unroll
            for (int j = 0; j < 4; ++j) {
                a[2*j]   += __uint_as_float(p0[j] << 16);
                a[2*j+1] += __uint_as_float(p0[j] & 0xffff0000u);
            }
        }
        float inv = 1.0f / (float)(deg > 1 ? deg : 1);
        float4 o0, o1;
        o0.x = a[0]*inv; o0.y = a[1]*inv; o0.z = a[2]*inv; o0.w = a[3]*inv;
        o1.x = a[4]*inv; o1.y = a[5]*inv; o1.z = a[6]*inv; o1.w = a[7]*inv;
        float* op = &out[(size_t)n * OUT_CH + l * 8];
        ((float4*)op)[0] = o0;
        ((float4*)op)[1] = o1;
    }
}

extern "C" void kernel_launch(void* const* d_in, const int* in_sizes, int n_in,
                              void* d_out, int out_size, void* d_ws, size_t ws_size,
                              hipStream_t stream) {
    const float* x  = (const float*)d_in[0];
    const int*   ei = (const int*)d_in[1];     // [2][E]: src then dst
    const float* W  = (const float*)d_in[2];
    const float* b  = (const float*)d_in[3];
    float* out = (float*)d_out;

    const int* src = ei;
    const int* dst = ei + N_EDGES;

    // workspace: linbf 12.8MB | Wbf 64KB | rec 4.8MB | bcnt
    char* ws = (char*)d_ws;
    short*    linbf = (short*)ws;    ws += ((size_t)N_NODES * OUT_CH * sizeof(short) + 255) & ~255ull;
    short*    Wbf   = (short*)ws;    ws += ((size_t)IN_CH * OUT_CH * sizeof(short) + 255) & ~255ull;
    unsigned* rec   = (unsigned*)ws; ws += ((size_t)NB * CAP * sizeof(unsigned) + 255) & ~255ull;
    int*      bcnt  = (int*)ws;

    convert_w<<<16, 256, 0, stream>>>(W, Wbf, bcnt);
    gemm_bucket<<<NGEMM + NB, 256, 0, stream>>>(x, Wbf, b, linbf, src, dst, bcnt, rec);
    fine_gather<<<NB, FG_THR, 0, stream>>>(bcnt, rec, linbf, out);
}